// Round 1
// 596.391 us; speedup vs baseline: 1.0165x; 1.0165x over previous
//
#include <hip/hip_runtime.h>

typedef float  f32x2  __attribute__((ext_vector_type(2)));
typedef float  f32x4  __attribute__((ext_vector_type(4)));
typedef __bf16 bf16x8 __attribute__((ext_vector_type(8)));

// split fp32 pair into packed bf16 hi-pair and lo-pair (3-term MFMA emulation)
static __device__ __forceinline__ void split_pair(float a, float b, unsigned& hp, unsigned& lp) {
    __bf16 ha = (__bf16)a, hb = (__bf16)b;
    hp = (unsigned)__builtin_bit_cast(unsigned short, ha) |
         ((unsigned)__builtin_bit_cast(unsigned short, hb) << 16);
    __bf16 la = (__bf16)(a - (float)ha), lb = (__bf16)(b - (float)hb);
    lp = (unsigned)__builtin_bit_cast(unsigned short, la) |
         ((unsigned)__builtin_bit_cast(unsigned short, lb) << 16);
}

// ============ CSR bucket build (order-free; buckets padded to multiple of 8) ============
__global__ __launch_bounds__(256) void hist_rows(const int* __restrict__ row, int* __restrict__ cnt, int E) {
    int e = blockIdx.x * 256 + threadIdx.x;
    if (e < E) atomicAdd(&cnt[row[e]], 1);
}

// also writes the pad slots {0, norm=0} directly -> no 9.6MB edge2 memset needed
__global__ __launch_bounds__(256) void alloc_buckets(const int* __restrict__ cnt,
                                                     int* __restrict__ base, int* __restrict__ fill,
                                                     float* __restrict__ dinv,
                                                     int* __restrict__ total,
                                                     int2* __restrict__ edge2, int n) {
    int i = blockIdx.x * 256 + threadIdx.x;
    if (i >= n) return;
    int c = cnt[i];
    int cp = (c + 7) & ~7;                 // pad to x8
    int b = atomicAdd(total, cp);
    base[i] = b;
    fill[i] = b;
    dinv[i] = rsqrtf(1.0f + (float)c);     // +1 self-loop
    for (int p = b + c; p < b + cp; ++p) edge2[p] = make_int2(0, 0);  // pad: gathers x[0]*0.0
}

__global__ __launch_bounds__(256) void fill_buckets(const int* __restrict__ row, const int* __restrict__ col,
                                                    int* __restrict__ fill, const float* __restrict__ dinv,
                                                    int2* __restrict__ edge2, int E) {
    int e = blockIdx.x * 256 + threadIdx.x;
    if (e < E) {
        int r = row[e], c = col[e];
        int pos = atomicAdd(&fill[r], 1);
        edge2[pos] = make_int2(c, __float_as_int(dinv[r] * dinv[c]));
    }
}

// ============ aggregate x (128 feats, float2/lane), software-pipelined edge blocks ============
__global__ __launch_bounds__(256) void agg_x(const float* __restrict__ x,
                                             const int* __restrict__ base, const int* __restrict__ cnt,
                                             const int2* __restrict__ edge2, const float* __restrict__ dinv,
                                             float* __restrict__ AGGX, int n) {
    int w = (blockIdx.x * 256 + threadIdx.x) >> 6;
    int lane = threadIdx.x & 63;
    if (w >= n) return;
    float di = dinv[w];
    f32x2 xv = ((const f32x2*)(x + (size_t)w * 128))[lane];
    f32x2 a0 = xv * (di * di);
    f32x2 a1 = {0.f, 0.f}, a2 = {0.f, 0.f}, a3 = {0.f, 0.f};
    const int2* eb = edge2 + base[w];
    int dp = (cnt[w] + 7) & ~7;
    if (dp > 0) {
        int2 e[8];
        #pragma unroll
        for (int u = 0; u < 8; ++u) e[u] = eb[u];
        int j = 0;
        for (; j + 8 < dp; j += 8) {           // all blocks except the last
            f32x2 v[8];
            #pragma unroll
            for (int u = 0; u < 8; ++u)        // 8 gathers in flight
                v[u] = ((const f32x2*)(x + (size_t)e[u].x * 128))[lane];
            int2 en[8];                        // prefetch next descriptor block under the gathers
            #pragma unroll
            for (int u = 0; u < 8; ++u) en[u] = eb[j + 8 + u];
            #pragma unroll
            for (int u = 0; u < 8; ++u) {
                float nr = __int_as_float(e[u].y);
                f32x2* a = (u & 3) == 0 ? &a0 : (u & 3) == 1 ? &a1 : (u & 3) == 2 ? &a2 : &a3;
                *a += v[u] * nr;
            }
            #pragma unroll
            for (int u = 0; u < 8; ++u) e[u] = en[u];
        }
        {   // tail block
            f32x2 v[8];
            #pragma unroll
            for (int u = 0; u < 8; ++u)
                v[u] = ((const f32x2*)(x + (size_t)e[u].x * 128))[lane];
            #pragma unroll
            for (int u = 0; u < 8; ++u) {
                float nr = __int_as_float(e[u].y);
                f32x2* a = (u & 3) == 0 ? &a0 : (u & 3) == 1 ? &a1 : (u & 3) == 2 ? &a2 : &a3;
                *a += v[u] * nr;
            }
        }
    }
    f32x2 o = a0 + a1 + a2 + a3;
    // nt store: AGGX is read-once streaming -> keep x resident in L2 instead
    __builtin_nontemporal_store(o, (f32x2*)(AGGX + (size_t)w * 128) + lane);
}

// ============ aggregate H2 (64 feats, 1 float/lane) + bias, software-pipelined ============
__global__ __launch_bounds__(256) void agg_h2(const float* __restrict__ H2,
                                              const int* __restrict__ base, const int* __restrict__ cnt,
                                              const int2* __restrict__ edge2, const float* __restrict__ dinv,
                                              const float* __restrict__ b2,
                                              float* __restrict__ AGG2, int n) {
    int w = (blockIdx.x * 256 + threadIdx.x) >> 6;
    int lane = threadIdx.x & 63;
    if (w >= n) return;
    float di = dinv[w];
    float a0 = H2[(size_t)w * 64 + lane] * di * di;
    float a1 = 0.f, a2 = 0.f, a3 = 0.f;
    const int2* eb = edge2 + base[w];
    int dp = (cnt[w] + 7) & ~7;
    if (dp > 0) {
        int2 e[8];
        #pragma unroll
        for (int u = 0; u < 8; ++u) e[u] = eb[u];
        int j = 0;
        for (; j + 8 < dp; j += 8) {
            float v[8];
            #pragma unroll
            for (int u = 0; u < 8; ++u)
                v[u] = H2[(size_t)e[u].x * 64 + lane];
            int2 en[8];
            #pragma unroll
            for (int u = 0; u < 8; ++u) en[u] = eb[j + 8 + u];
            #pragma unroll
            for (int u = 0; u < 8; ++u) {
                float nr = __int_as_float(e[u].y);
                float* a = (u & 3) == 0 ? &a0 : (u & 3) == 1 ? &a1 : (u & 3) == 2 ? &a2 : &a3;
                *a = fmaf(v[u], nr, *a);
            }
            #pragma unroll
            for (int u = 0; u < 8; ++u) e[u] = en[u];
        }
        {
            float v[8];
            #pragma unroll
            for (int u = 0; u < 8; ++u)
                v[u] = H2[(size_t)e[u].x * 64 + lane];
            #pragma unroll
            for (int u = 0; u < 8; ++u) {
                float nr = __int_as_float(e[u].y);
                float* a = (u & 3) == 0 ? &a0 : (u & 3) == 1 ? &a1 : (u & 3) == 2 ? &a2 : &a3;
                *a = fmaf(v[u], nr, *a);
            }
        }
    }
    float o = a0 + a1 + a2 + a3 + b2[lane];
    __builtin_nontemporal_store(o, AGG2 + (size_t)w * 64 + lane);   // read-once by final_out
}

// ============ MFMA GEMM: C = A[M,K]@B[K,N] (+bias, relu), fp32 via bf16 hi/lo 3-term split ============
// 64x64 tile, 4 waves (32x32 quadrant each), 2x2 16x16x32 fragments, BK=32.
// LDS layout [g(4)][row(64)][jpair(4 uints)]: fragment read = one contiguous ds_read_b128.
// Fragment mapping (m89-verified family): A: row=lane&15, k=(lane>>4)*8+j; B mirrored; D: col=lane&15, row=(lane>>4)*4+reg.
template<int NT_IN, int NT_OUT>
__global__ __launch_bounds__(256) void gemm_mfma(const float* __restrict__ A,
                                                 const float* __restrict__ B,
                                                 const float* __restrict__ bias,
                                                 float* __restrict__ C,
                                                 int M, int N, int K, int relu) {
    __shared__ unsigned Ah[4][64][4], Al[4][64][4], Bh[4][64][4], Bl[4][64][4];  // 16 KiB

    // XCD-chunked bijective swizzle (m204): blocks sharing an A row-panel land on one XCD's L2
    const int nbn = gridDim.x;                       // 4 (gemm1) or 1 (gemm2) -> power of 2
    const int nl  = (nbn == 4) ? 2 : 0;
    const int tot = nbn * gridDim.y;
    int flat = blockIdx.x + nbn * blockIdx.y;
    int q = tot >> 3, r = tot & 7;
    int x8 = flat & 7, i8 = flat >> 3;
    int f2 = (x8 < r ? x8 * (q + 1) : r * (q + 1) + (x8 - r) * q) + i8;
    const int bn = (f2 & (nbn - 1)) * 64;
    const int bm = (f2 >> nl) * 64;

    const int tid  = threadIdx.x;
    const int lane = tid & 63;
    const int wv   = tid >> 6;
    const int wr   = wv >> 1, wc = wv & 1;           // wave's 32x32 quadrant
    const int lg   = lane >> 4, lr = lane & 15;

    f32x4 acc[2][2] = {};

    for (int k0 = 0; k0 < K; k0 += 32) {
        // ---- stage A 64x32: thread handles 4 float2 (2 consecutive k) ----
        #pragma unroll
        for (int i = 0; i < 4; ++i) {
            int t  = tid + i * 256;                  // 0..1023
            int rr = t >> 4;                         // row 0..63
            int kp = t & 15;                         // k-pair 0..15
            int gr = bm + rr;
            f32x2 v = {0.f, 0.f};
            if (gr < M) {
                const f32x2* p = (const f32x2*)(A + (size_t)gr * K + k0 + 2 * kp);
                v = NT_IN ? __builtin_nontemporal_load(p) : *p;
            }
            unsigned hp, lp;
            split_pair(v.x, v.y, hp, lp);
            Ah[kp >> 2][rr][kp & 3] = hp;
            Al[kp >> 2][rr][kp & 3] = lp;
        }
        // ---- stage B 32x64: thread handles one col, 2 consecutive k ----
        #pragma unroll
        for (int i = 0; i < 4; ++i) {
            int t  = tid + i * 256;
            int cc = t & 63;
            int kp = t >> 6;                         // 0..15
            const float* p = B + (size_t)(k0 + 2 * kp) * N + bn + cc;
            float v0 = p[0], v1 = p[N];              // W matrices stay cached
            unsigned hp, lp;
            split_pair(v0, v1, hp, lp);
            Bh[kp >> 2][cc][kp & 3] = hp;
            Bl[kp >> 2][cc][kp & 3] = lp;
        }
        __syncthreads();

        bf16x8 ah[2], al[2], bh[2], bl[2];
        #pragma unroll
        for (int f = 0; f < 2; ++f) {
            int ar = wr * 32 + f * 16 + lr;
            ah[f] = *(const bf16x8*)&Ah[lg][ar][0];
            al[f] = *(const bf16x8*)&Al[lg][ar][0];
            int bc = wc * 32 + f * 16 + lr;
            bh[f] = *(const bf16x8*)&Bh[lg][bc][0];
            bl[f] = *(const bf16x8*)&Bl[lg][bc][0];
        }
        #pragma unroll
        for (int fi = 0; fi < 2; ++fi)
            #pragma unroll
            for (int fj = 0; fj < 2; ++fj) {
                acc[fi][fj] = __builtin_amdgcn_mfma_f32_16x16x32_bf16(ah[fi], bh[fj], acc[fi][fj], 0, 0, 0);
                acc[fi][fj] = __builtin_amdgcn_mfma_f32_16x16x32_bf16(ah[fi], bl[fj], acc[fi][fj], 0, 0, 0);
                acc[fi][fj] = __builtin_amdgcn_mfma_f32_16x16x32_bf16(al[fi], bh[fj], acc[fi][fj], 0, 0, 0);
            }
        __syncthreads();
    }

    // ---- epilogue ----
    #pragma unroll
    for (int fj = 0; fj < 2; ++fj) {
        int col = bn + wc * 32 + fj * 16 + lr;
        float bv = bias ? bias[col] : 0.f;
        #pragma unroll
        for (int fi = 0; fi < 2; ++fi) {
            #pragma unroll
            for (int rg = 0; rg < 4; ++rg) {
                int gr = bm + wr * 32 + fi * 16 + lg * 4 + rg;
                if (gr < M) {
                    float o = acc[fi][fj][rg] + bv;
                    if (relu) o = fmaxf(o, 0.f);
                    if (NT_OUT) __builtin_nontemporal_store(o, C + (size_t)gr * N + col);
                    else        C[(size_t)gr * N + col] = o;
                }
            }
        }
    }
}

// ============ log_softmax (wave64 = 64 feats) + broadcast 24 copies, all non-temporal ============
__global__ __launch_bounds__(256) void final_out(const float* __restrict__ AGG2,
                                                 float* __restrict__ out, int n, int copies) {
    int w = (blockIdx.x * 256 + threadIdx.x) >> 6;
    int lane = threadIdx.x & 63;
    if (w >= n) return;
    size_t idx = (size_t)w * 64 + lane;
    float v = __builtin_nontemporal_load(AGG2 + idx);
    float m = v;
    #pragma unroll
    for (int off = 32; off > 0; off >>= 1) m = fmaxf(m, __shfl_xor(m, off, 64));
    float e = expf(v - m);
    float s = e;
    #pragma unroll
    for (int off = 32; off > 0; off >>= 1) s += __shfl_xor(s, off, 64);
    float res = v - m - logf(s);
    size_t stride = (size_t)n * 64;
    for (int c = 0; c < copies; ++c)
        __builtin_nontemporal_store(res, out + (size_t)c * stride + idx);
}

extern "C" void kernel_launch(void* const* d_in, const int* in_sizes, int n_in,
                              void* d_out, int out_size, void* d_ws, size_t ws_size,
                              hipStream_t stream) {
    const float* x  = (const float*)d_in[0];
    const float* W1 = (const float*)d_in[1];
    const float* b1 = (const float*)d_in[2];
    const float* W2 = (const float*)d_in[3];
    const float* b2 = (const float*)d_in[4];
    const int*   ei = (const int*)d_in[5];

    const int n = in_sizes[0] / 128;              // 50000
    const int E = in_sizes[5] / 2;                // 800000
    float* out = (float*)d_out;
    const size_t stride = (size_t)n * 64;         // one broadcast-copy region (3.2M floats)
    const int copies = (int)(out_size / stride);  // 24

    // ---- d_out doubles as workspace (regions dead or same-wave-read before final_out) ----
    float* dinv  = out;                           // region 0
    int*   cnt   = (int*)(out + n);
    int*   base  = (int*)(out + 2 * (size_t)n);
    int*   fill  = (int*)(out + 3 * (size_t)n);
    int*   total = (int*)(out + 4 * (size_t)n);
    int2*  edge2 = (int2*)(out + 1 * stride);     // region 1: (E + 8n) int2 = 9.6 MB < 12.8 MB
    float* AGGX  = out + 2 * stride;              // regions 2-3
    float* H1    = out + 4 * stride;              // regions 4-7
    float* H2    = out + 8 * stride;              // region 8
    float* AGG2  = out + 9 * stride;              // region 9

    // zero cnt/base/fill/total only (edge2 pads now written by alloc_buckets)
    hipMemsetAsync(cnt, 0, (3 * (size_t)n + 64) * sizeof(int), stream);

    // bucket build
    hist_rows    <<<(E + 255) / 256, 256, 0, stream>>>(ei, cnt, E);
    alloc_buckets<<<(n + 255) / 256, 256, 0, stream>>>(cnt, base, fill, dinv, total, edge2, n);
    fill_buckets <<<(E + 255) / 256, 256, 0, stream>>>(ei, ei + E, fill, dinv, edge2, E);

    // layer 1: aggregate-then-transform (A(xW) == (Ax)W)
    agg_x<<<(n + 3) / 4, 256, 0, stream>>>(x, base, cnt, edge2, dinv, AGGX, n);
    // H1 is read exactly once (by gemm2) -> NT_OUT; AGGX reused 4x across bn-blocks -> cached reads
    gemm_mfma<0, 1><<<dim3(4, (n + 63) / 64), 256, 0, stream>>>(AGGX, W1, b1, H1, n, 256, 128, 1);

    // layer 2: transform-then-aggregate (64 < 256 feats)
    // H1 read-once -> NT_IN; H2 gathered 16x by agg_h2 -> cached (NT_OUT=0)
    gemm_mfma<1, 0><<<dim3(1, (n + 63) / 64), 256, 0, stream>>>(H1, W2, nullptr, H2, n, 64, 256, 0);
    agg_h2<<<(n + 3) / 4, 256, 0, stream>>>(H2, base, cnt, edge2, dinv, b2, AGG2, n);

    // log_softmax + broadcast (overwrites every byte of d_out)
    final_out<<<(n + 3) / 4, 256, 0, stream>>>(AGG2, out, n, copies);
}